// Round 6
// baseline (325.831 us; speedup 1.0000x reference)
//
#include <hip/hip_runtime.h>
#include <math.h>

#define BB 32
#define CC 256
#define HH 56
#define WW 56
#define KP 49      // 7*7 output pixels of the small convs
#define CMID 64    // C // RED
#define HW 3136    // 56*56

// ---- K0: fused  pool (blocks 0..2047)  +  LDS-tiled weight transpose ----
__global__ __launch_bounds__(256) void pre_kernel(const float* __restrict__ x,
                                                  const float* __restrict__ w1,
                                                  const float* __restrict__ w2,
                                                  float* __restrict__ pooled,
                                                  float* __restrict__ w1t,
                                                  float* __restrict__ w2t) {
    int bid = blockIdx.x;
    if (bid < 2048) {
        // pool: 4 planes per block, wave = plane, lane = 7x7 output window
        int wv = threadIdx.x >> 6, lane = threadIdx.x & 63;
        int g = bid * 4 + wv;               // plane id = b*256 + c
        if (lane < KP) {
            int ko = lane / 7, kw = lane - ko * 7;
            const float* base = x + (size_t)g * HW + (ko * 8) * WW + kw * 8;
            float s = 0.f;
            #pragma unroll
            for (int r = 0; r < 8; ++r) {
                float4 a = *(const float4*)(base + r * WW);
                float4 b4 = *(const float4*)(base + r * WW + 4);
                s += a.x + a.y + a.z + a.w + b4.x + b4.y + b4.z + b4.w;
            }
            pooled[(size_t)g * KP + lane] = s * (1.f / 64.f);
        }
        return;
    }
    // LDS-tiled transpose: coalesced read AND write (65-float stride = no conflicts)
    __shared__ float t[64][65];
    int r = threadIdx.x >> 6, c = threadIdx.x & 63;
    if (bid < 2048 + 36) {                  // w1: (64co, 2304ct) -> w1t (2304, 64)
        int ct0 = (bid - 2048) * 64;
        #pragma unroll
        for (int i = 0; i < 16; ++i)
            t[r + 4 * i][c] = w1[(size_t)(r + 4 * i) * 2304 + ct0 + c];
        __syncthreads();
        #pragma unroll
        for (int i = 0; i < 16; ++i)
            w1t[(size_t)(ct0 + r + 4 * i) * 64 + c] = t[c][r + 4 * i];
    } else {                                // w2: (512co, 576ct) -> w2t (576, 512)
        int tt = bid - 2048 - 36;
        int co0 = (tt / 9) * 64, ct0 = (tt % 9) * 64;
        #pragma unroll
        for (int i = 0; i < 16; ++i)
            t[r + 4 * i][c] = w2[(size_t)(co0 + r + 4 * i) * 576 + ct0 + c];
        __syncthreads();
        #pragma unroll
        for (int i = 0; i < 16; ++i)
            w2t[(size_t)(ct0 + r + 4 * i) * 512 + co0 + c] = t[c][r + 4 * i];
    }
}

// ---- K1: FUSED conv1(+BN+GELU) + conv2(+bias+softmax+mix), one launch ------
// Block (y, b): phase 1 computes the 3 hmid rows (y-1, y, y+1) this block's
// conv2 row needs (redundant 3x conv1 work -- trivial FLOPs) into LDS;
// phase 2 = conv2 row y reading hmid from LDS. Kills one kernel launch and
// the hmid global round-trip.
__global__ __launch_bounds__(1024) void convfused_kernel(const float* __restrict__ pooled,
                                                         const float* __restrict__ w1t,
                                                         const float* __restrict__ gamma,
                                                         const float* __restrict__ beta,
                                                         const float* __restrict__ w2t,
                                                         const float* __restrict__ b2,
                                                         const float* __restrict__ wdyn,
                                                         float* __restrict__ dynw) {
    int y = blockIdx.x, b = blockIdx.y;
    __shared__ float red16[16][3][7][64];     // 86 KB; phase-2 aliases it
    __shared__ float hmid3[CMID][22];         // 3 rows x 7 cols per mid-channel

    // ---------------- phase 1: conv1 partials, 16 waves x 16 cins ----------
    {
        int wv = threadIdx.x >> 6, co = threadIdx.x & 63;
        float acc3[3][7] = {};
        const float* pb = pooled + (size_t)b * CC * KP;
        int cin0 = __builtin_amdgcn_readfirstlane(wv * 16);
        #pragma unroll 2
        for (int ci = 0; ci < 16; ++ci) {
            int cin = cin0 + ci;
            const float* prow_base = pb + cin * KP;
            const float* wbase = w1t + (size_t)(cin * 9) * 64 + co;
            float wv0[3], wv1[3], wv2[3];
            #pragma unroll
            for (int ky = 0; ky < 3; ++ky) {
                const float* wr = wbase + ky * 192;
                wv0[ky] = wr[0]; wv1[ky] = wr[64]; wv2[ky] = wr[128];
            }
            // rolling window: row rr feeds all (d,ky) pairs with d+ky == rr
            #pragma unroll
            for (int rr = 0; rr < 5; ++rr) {
                int iy = y - 2 + rr;
                float s[9];
                s[0] = 0.f; s[8] = 0.f;
                if (0 <= iy && iy < 7) {                  // uniform branch
                    const float* pr = prow_base + iy * 7; // uniform -> s_load
                    #pragma unroll
                    for (int j = 0; j < 7; ++j) s[j + 1] = pr[j];
                } else {
                    #pragma unroll
                    for (int j = 0; j < 7; ++j) s[j + 1] = 0.f;
                }
                #pragma unroll
                for (int ky = 0; ky < 3; ++ky) {
                    int d = rr - ky;                      // output row y-1+d
                    if (0 <= d && d < 3) {
                        #pragma unroll
                        for (int xx = 0; xx < 7; ++xx)
                            acc3[d][xx] += s[xx] * wv0[ky] + s[xx + 1] * wv1[ky]
                                         + s[xx + 2] * wv2[ky];
                    }
                }
            }
        }
        #pragma unroll
        for (int d = 0; d < 3; ++d)
            #pragma unroll
            for (int xx = 0; xx < 7; ++xx)
                red16[wv][d][xx][co] = acc3[d][xx];
    }
    __syncthreads();
    // 16-way reduce + BN + exact GELU -> hmid3 (rows y-1..y+1; OOB rows junk,
    // never read by phase 2's iy guard)
    for (int idx = threadIdx.x; idx < 3 * 7 * 64; idx += 1024) {
        int c2 = idx & 63, rest = idx >> 6;
        int d = rest / 7, xx = rest - d * 7;
        float tot = 0.f;
        #pragma unroll
        for (int w = 0; w < 16; ++w) tot += red16[w][d][xx][c2];
        float bnscale = gamma[c2] * rsqrtf(1.f + 1e-5f);
        float h = tot * bnscale + beta[c2];
        float g = 0.5f * h * (1.f + erff(h * 0.70710678118654752440f));
        hmid3[c2][d * 7 + xx] = g;
    }
    __syncthreads();

    // ---------------- phase 2: conv2 row y, 4 ci-quarters x 256 co ---------
    float (*redA)[7][256] = (float (*)[7][256])(&red16[0][0][0][0]);
    float (*redB)[7][256] = (float (*)[7][256])(&red16[0][0][0][0] + 4 * 7 * 256);
    {
        int qq = threadIdx.x >> 8, co = threadIdx.x & 255;
        float a0[7] = {}, a1[7] = {};
        int cin0 = __builtin_amdgcn_readfirstlane(qq * 16);
        #pragma unroll 2
        for (int ci = 0; ci < 16; ++ci) {
            int cin = cin0 + ci;
            const float* wbase = w2t + (size_t)(cin * 9) * 512 + co;
            #pragma unroll
            for (int ky = 0; ky < 3; ++ky) {
                int iy = y + ky - 1;
                if (0 <= iy && iy < 7) {                  // uniform branch
                    float s[9];
                    s[0] = 0.f; s[8] = 0.f;
                    const float* hr = &hmid3[cin][ky * 7]; // LDS broadcast read
                    #pragma unroll
                    for (int j = 0; j < 7; ++j) s[j + 1] = hr[j];
                    const float* wr = wbase + ky * 3 * 512;
                    float wa0 = wr[0],    wb0 = wr[256];
                    float wa1 = wr[512],  wb1 = wr[768];
                    float wa2 = wr[1024], wb2 = wr[1280];
                    #pragma unroll
                    for (int xx = 0; xx < 7; ++xx) {
                        float v0 = s[xx], v1 = s[xx + 1], v2 = s[xx + 2];
                        a0[xx] += v0 * wa0 + v1 * wa1 + v2 * wa2;
                        a1[xx] += v0 * wb0 + v1 * wb1 + v2 * wb2;
                    }
                }
            }
        }
        #pragma unroll
        for (int xx = 0; xx < 7; ++xx) { redA[qq][xx][co] = a0[xx]; redB[qq][xx][co] = a1[xx]; }
    }
    __syncthreads();
    if (threadIdx.x < 256) {
        int c = threadIdx.x;
        float bias0 = b2[c], bias1 = b2[c + CC];
        const float* wd0 = wdyn + (size_t)c * KP + y * 7;
        const float* wd1 = wdyn + (size_t)(CC + c) * KP + y * 7;
        float* dw = dynw + ((size_t)(b * CC + c)) * KP + y * 7;
        #pragma unroll
        for (int xx = 0; xx < 7; ++xx) {
            float s0 = redA[0][xx][c] + redA[1][xx][c] + redA[2][xx][c] + redA[3][xx][c] + bias0;
            float s1 = redB[0][xx][c] + redB[1][xx][c] + redB[2][xx][c] + redB[3][xx][c] + bias1;
            float m = fmaxf(s0, s1);
            float e0 = expf(s0 - m), e1 = expf(s1 - m);
            dw[xx] = (e0 * wd0[xx] + e1 * wd1[xx]) / (e0 + e1);
        }
    }
}

// ---- K2: depthwise 7x7, NO LDS, 2 waves/plane, 2-deep row-load pipeline ----
// Lane tile 7 rows x 4 cols (acc 28 regs, was 56): more resident waves.
// Per row: 3 aligned float4 loads; next row's loads issued BEFORE current
// row's 196 FMAs so L2 latency (~200-400cy) hides under compute (~392cy).
__global__ __launch_bounds__(256) void dwconv_kernel(const float* __restrict__ x,
                                                     const float* __restrict__ dynw,
                                                     float* __restrict__ out) {
    int tid = threadIdx.x & 63;
    int wv = threadIdx.x >> 6;                   // 0..3
    int p = wv >> 1, sub = wv & 1;               // plane-in-block, col half
    int g = __builtin_amdgcn_readfirstlane(blockIdx.x * 2 + p);

    const float* wp = dynw + (size_t)g * KP;     // uniform -> s_load
    float w[49];
    #pragma unroll
    for (int i = 0; i < 49; ++i) w[i] = wp[i];

    if (tid < 56) {
        int ty = tid / 7, tx = tid - ty * 7;     // ty 0..7, tx 0..6
        int r0 = 7 * ty;
        int c0 = 28 * sub + 4 * tx;              // 4-col tile, 16B aligned
        const float* xp = x + (size_t)g * HW;
        float acc[7][4] = {};
        float rbA[12], rbB[12];                  // rb[j] = data col c0-4+j

#define LOADR(IR, RB) { \
        int r = r0 + (IR) - 3; \
        bool rowok = (unsigned)r < 56u; \
        int rbase = r * WW; \
        _Pragma("unroll") \
        for (int k = 0; k < 3; ++k) { \
            int w0c = c0 - 4 + 4 * k; \
            bool ok = rowok && ((unsigned)w0c < 56u); \
            int off = ok ? (rbase + w0c) : 0; \
            float4 v = *(const float4*)(xp + off); \
            if (!ok) v = make_float4(0.f, 0.f, 0.f, 0.f); \
            RB[4*k+0] = v.x; RB[4*k+1] = v.y; RB[4*k+2] = v.z; RB[4*k+3] = v.w; \
        } }

#define COMPR(IR, RB) { \
        _Pragma("unroll") \
        for (int ky = 0; ky < 7; ++ky) { \
            int oy = (IR) - ky; \
            if (0 <= oy && oy < 7) { \
                _Pragma("unroll") \
                for (int kx = 0; kx < 7; ++kx) { \
                    float ww = w[ky * 7 + kx]; \
                    _Pragma("unroll") \
                    for (int ox = 0; ox < 4; ++ox) \
                        acc[oy][ox] += RB[ox + kx + 1] * ww; \
                } } } }

        LOADR(0, rbA)
        #pragma unroll
        for (int ii = 0; ii < 6; ++ii) {
            LOADR(2 * ii + 1, rbB)
            COMPR(2 * ii,     rbA)
            LOADR(2 * ii + 2, rbA)
            COMPR(2 * ii + 1, rbB)
        }
        COMPR(12, rbA)
#undef LOADR
#undef COMPR

        float* op = out + (size_t)g * HW;
        #pragma unroll
        for (int oy = 0; oy < 7; ++oy)
            *(float4*)(op + (r0 + oy) * WW + c0) =
                make_float4(acc[oy][0], acc[oy][1], acc[oy][2], acc[oy][3]);
    }
}

extern "C" void kernel_launch(void* const* d_in, const int* in_sizes, int n_in,
                              void* d_out, int out_size, void* d_ws, size_t ws_size,
                              hipStream_t stream) {
    const float* x     = (const float*)d_in[0];  // (32,256,56,56)
    const float* wdyn  = (const float*)d_in[1];  // (2,256,7,7)
    const float* w1    = (const float*)d_in[2];  // (64,256,3,3)
    const float* gamma = (const float*)d_in[3];  // (64,)
    const float* beta  = (const float*)d_in[4];  // (64,)
    const float* w2    = (const float*)d_in[5];  // (512,64,3,3)
    const float* b2    = (const float*)d_in[6];  // (512,)
    float* out = (float*)d_out;

    float* ws     = (float*)d_ws;
    float* pooled = ws;               // 401408 floats
    float* dynw   = ws + 501760;      // 401408 floats
    float* w1t    = ws + 903168;      // 147456 floats
    float* w2t    = ws + 1050624;     // 294912 floats  (total 5.2 MB)

    pre_kernel      <<<dim3(2048 + 36 + 72),  256, 0, stream>>>(x, w1, w2, pooled, w1t, w2t);
    convfused_kernel<<<dim3(7, BB),          1024, 0, stream>>>(pooled, w1t, gamma, beta,
                                                               w2t, b2, wdyn, dynw);
    dwconv_kernel   <<<dim3(BB * CC / 2),     256, 0, stream>>>(x, dynw, out);
}